// Round 8
// baseline (1263.586 us; speedup 1.0000x reference)
//
#include <hip/hip_runtime.h>

// Problem constants
#define V 100000
#define E_EDGES 524288
#define HALF 262144
#define D 128
#define NREL 474
#define BN_EPS 1e-5f

#define LDK 392   // A-tile LDS row stride in u16 (384 + 8 pad, rows 16B-aligned)
#define LDB 40    // B-tile LDS row stride in u16 (32 + 8 pad)

// milestone / flag indices in done[]
#define MS_HIST   0
#define MS_SCAN   1
#define MS_FILL   2
#define MS_FUSED  3
#define MS_BNFIN  4
#define MS_BNRELU 5
#define MS_RELG   6
#define POSFLAG   7   // any positive BN output was written

typedef unsigned short u16;
typedef unsigned int u32;
typedef __attribute__((ext_vector_type(8))) short short8;
typedef __attribute__((ext_vector_type(4))) float f32x4;

__device__ __forceinline__ u16 f2bf(float f) {
    union { float f; u32 u; } v; v.f = f;
    u32 u = v.u;
    return (u16)((u + 0x7fffu + ((u >> 16) & 1u)) >> 16);  // RNE
}
__device__ __forceinline__ u32 pk2(float a, float b) {
    return (u32)f2bf(a) | ((u32)f2bf(b) << 16);
}

// ---------------------------------------------------------------------------
// K1: histogram of dst (index-clamped)
// ---------------------------------------------------------------------------
__global__ __launch_bounds__(256) void hist_k(const int* __restrict__ dst, u32* __restrict__ cnt,
                                              u32* __restrict__ done) {
    int e = blockIdx.x * 256 + threadIdx.x;
    if (blockIdx.x == 0 && threadIdx.x == 0) done[MS_HIST] = 1u;
    if (e >= E_EDGES) return;
    u32 d = (u32)dst[e];
    if (d >= V) d = 0;
    atomicAdd(&cnt[d], 1u);
}

// ---------------------------------------------------------------------------
// K2: exclusive scan of cnt[V] -> cursor (single 1024-thread block)
// ---------------------------------------------------------------------------
__global__ __launch_bounds__(1024) void scan_k(const u32* __restrict__ cnt,
                                               u32* __restrict__ cursor, u32* __restrict__ done) {
    __shared__ u32 wsum[16];
    __shared__ u32 carry_s;
    int tid = threadIdx.x, wid = tid >> 6, lane = tid & 63;
    if (tid == 0) { carry_s = 0; done[MS_SCAN] = 1u; }
    __syncthreads();
    for (int base = 0; base < V; base += 1024) {
        int idx = base + tid;
        u32 v = (idx < V) ? cnt[idx] : 0u;
        u32 s = v;
#pragma unroll
        for (int o = 1; o < 64; o <<= 1) {
            u32 t = __shfl_up(s, o, 64);
            if (lane >= o) s += t;
        }
        if (lane == 63) wsum[wid] = s;
        __syncthreads();
        if (wid == 0) {
            u32 wv = (lane < 16) ? wsum[lane] : 0u;
#pragma unroll
            for (int o = 1; o < 16; o <<= 1) {
                u32 t = __shfl_up(wv, o, 64);
                if (lane >= o) wv += t;
            }
            if (lane < 16) wsum[lane] = wv;
        }
        __syncthreads();
        u32 wprev = (wid == 0) ? 0u : wsum[wid - 1];
        u32 c = carry_s;
        if (idx < V) cursor[idx] = c + s + wprev - v;   // exclusive prefix
        u32 tot = wsum[15];
        __syncthreads();
        if (tid == 0) carry_s = c + tot;
        __syncthreads();
    }
}

// ---------------------------------------------------------------------------
// K3: bucket-fill: eid[slot] = edge id, sorted by dst.
// Post: cursor[v] = bucket end; beg = cursor[v] - cnt[v].
// ---------------------------------------------------------------------------
__global__ __launch_bounds__(256) void fill_k(
    const int* __restrict__ dst, u32* __restrict__ cursor, u32* __restrict__ eid,
    u32* __restrict__ done) {
    int e = blockIdx.x * 256 + threadIdx.x;
    if (blockIdx.x == 0 && threadIdx.x == 0) done[MS_FILL] = 1u;
    if (e >= E_EDGES) return;
    u32 d = (u32)dst[e];
    if (d >= V) d = 0;
    u32 slot = atomicAdd(&cursor[d], 1u);
    if (slot < E_EDGES) eid[slot] = (u32)e;
}

// ---------------------------------------------------------------------------
// K4: fused gather + GEMM.  64 nodes/block, 256 threads, LDS = 60 KB.
// Phase A: per-wave serial gather of 16 rows -> bf16 A-tile [64 x 384]
//          ([agg_in | agg_out | x*loop_rel]) in LDS; f32 inputs.
// Phase B: A @ [in_w; out_w; loop_w] via 16x16x32 bf16 MFMA, h = /3,
//          f32 store to d_out (pre-BN), per-column sum/sumsq for BatchNorm.
// ---------------------------------------------------------------------------
__global__ __launch_bounds__(256, 1) void fused_k(
    const float* __restrict__ x, const float* __restrict__ rel, const float* __restrict__ loop_rel,
    const float* __restrict__ in_w, const float* __restrict__ out_w, const float* __restrict__ loop_w,
    const float* __restrict__ enorm,
    const int* __restrict__ src, const int* __restrict__ etype,
    const u32* __restrict__ cursor, const u32* __restrict__ cnt,
    const u32* __restrict__ eid,
    float* __restrict__ h_out, float* __restrict__ colsum, float* __restrict__ colsumsq,
    u32* __restrict__ done, float* __restrict__ hprobe) {
    __shared__ u16 Alds[64 * LDK];
    __shared__ u16 Bs[D * LDB];
    __shared__ float s_sum[D], s_sq[D];

    int tid = threadIdx.x, wave = tid >> 6, lane = tid & 63;
    int row0 = blockIdx.x * 64;

    if (tid < D) { s_sum[tid] = 0.f; s_sq[tid] = 0.f; }

    // ---- Phase A: gather (f32 loads) ----
    for (int i = 0; i < 16; i++) {
        int row = wave * 16 + i;
        int gv = row0 + row;
        u32* arow = (u32*)(Alds + row * LDK);
        if (gv < V) {
            float a0 = 0.f, a1 = 0.f, b0 = 0.f, b1 = 0.f;
            u32 n = cnt[gv];
            u32 end = cursor[gv];
            u32 beg = (end >= n) ? end - n : 0u;
            if (beg >= E_EDGES) { beg = 0; n = 0; }
            if (n > E_EDGES - beg) n = E_EDGES - beg;
            for (u32 p = beg; p < beg + n; ++p) {
                u32 e = eid[p];            if (e >= E_EDGES) e = 0;
                u32 s = (u32)src[e];       if (s >= V) s = 0;
                u32 t = (u32)etype[e];     if (t >= NREL) t = 0;
                float nm = enorm[e];
                float2 xv = *(const float2*)(x + (size_t)s * D + lane * 2);
                float2 rv = *(const float2*)(rel + (size_t)t * D + lane * 2);
                float f0 = xv.x * rv.x * nm;
                float f1 = xv.y * rv.y * nm;
                if (e < HALF) { a0 += f0; a1 += f1; }
                else          { b0 += f0; b1 += f1; }
            }
            float2 xv = *(const float2*)(x + (size_t)gv * D + lane * 2);
            float2 lv = *(const float2*)(loop_rel + lane * 2);
            arow[lane]       = pk2(a0, a1);                    // cols   0..127 (in)
            arow[64 + lane]  = pk2(b0, b1);                    // cols 128..255 (out)
            arow[128 + lane] = pk2(xv.x * lv.x, xv.y * lv.y);  // cols 256..383 (loop)
        } else {
            arow[lane] = 0u; arow[64 + lane] = 0u; arow[128 + lane] = 0u;
        }
    }
    __syncthreads();

    // ---- Phase B: GEMM  [64 x 384] @ [384 x 128] ----
    f32x4 acc[8];
#pragma unroll
    for (int ct = 0; ct < 8; ct++) acc[ct] = (f32x4){0.f, 0.f, 0.f, 0.f};

    int m = wave * 16 + (lane & 15);     // 0..63
    int kq = (lane >> 4) * 8;
    int bk = tid >> 3;                   // 0..31 : k within 32-step
    int bn0 = (tid & 7) * 16;            // 0..112 : n start

    for (int ks = 0; ks < 12; ks++) {
        int k0 = ks * 32;
        int seg = k0 >> 7;
        int kloc = k0 & 127;
        const float* W = (seg == 0) ? in_w : (seg == 1 ? out_w : loop_w);
#pragma unroll
        for (int j = 0; j < 16; j += 2) {
            float2 w2 = *(const float2*)(W + (size_t)(kloc + bk) * D + bn0 + j);
            Bs[(bn0 + j) * LDB + bk]     = f2bf(w2.x);
            Bs[(bn0 + j + 1) * LDB + bk] = f2bf(w2.y);
        }
        __syncthreads();
        short8 a = *(const short8*)(Alds + m * LDK + k0 + kq);
#pragma unroll
        for (int ct = 0; ct < 8; ct++) {
            short8 b = *(const short8*)(Bs + (ct * 16 + (lane & 15)) * LDB + kq);
            acc[ct] = __builtin_amdgcn_mfma_f32_16x16x32_bf16(a, b, acc[ct], 0, 0, 0);
        }
        __syncthreads();
    }

    // diagnostics: block 0 / thread 0 records accumulator magnitude + milestone
    if (blockIdx.x == 0 && tid == 0) {
        float s = 0.f;
#pragma unroll
        for (int ct = 0; ct < 8; ct++)
#pragma unroll
            for (int i = 0; i < 4; i++) s += fabsf(acc[ct][i]);
        hprobe[0] = s;
        done[MS_FUSED] = 1u;
    }

    // ---- epilogue: /3, f32 store to d_out, BN column stats ----
    int m4 = (lane >> 4) * 4;
#pragma unroll
    for (int ct = 0; ct < 8; ct++) {
        float ls = 0.f, lq = 0.f;
#pragma unroll
        for (int i = 0; i < 4; i++) {
            int gv = row0 + wave * 16 + m4 + i;
            if (gv < V) {
                float h = acc[ct][i] * (1.0f / 3.0f);
                h_out[(size_t)gv * D + ct * 16 + (lane & 15)] = h;
                ls += h; lq += h * h;
            }
        }
        atomicAdd(&s_sum[ct * 16 + (lane & 15)], ls);
        atomicAdd(&s_sq[ct * 16 + (lane & 15)], lq);
    }
    __syncthreads();
    if (tid < D) atomicAdd(&colsum[tid], s_sum[tid]);
    else atomicAdd(&colsumsq[tid - D], s_sq[tid - D]);
}

// ---------------------------------------------------------------------------
// K5: finalize BN stats
// ---------------------------------------------------------------------------
__global__ void bn_finalize(const float* __restrict__ colsum, const float* __restrict__ colsumsq,
                            float* __restrict__ mean, float* __restrict__ scale,
                            u32* __restrict__ done) {
    int t = threadIdx.x;
    float m = colsum[t] * (1.0f / (float)V);
    if (!isfinite(m)) m = 0.f;
    float var = colsumsq[t] * (1.0f / (float)V) - m * m;
    if (!isfinite(var) || var < 0.f) var = 0.f;
    mean[t] = m;
    scale[t] = rsqrtf(var + BN_EPS);
    if (t == 0) done[MS_BNFIN] = 1u;
}

// ---------------------------------------------------------------------------
// K6: in-place BN + ReLU on d_out (f32)
// ---------------------------------------------------------------------------
__global__ __launch_bounds__(256) void bn_relu(
    float* __restrict__ hio, const float* __restrict__ mean, const float* __restrict__ scale,
    u32* __restrict__ done) {
    if (blockIdx.x == 0 && threadIdx.x == 0) done[MS_BNRELU] = 1u;
    int idx = (blockIdx.x * 256 + threadIdx.x) * 4;
    if (idx >= V * D) return;
    int col = idx & (D - 1);
    float4 hv = *(const float4*)(hio + idx);
    float f0 = (hv.x - mean[col + 0]) * scale[col + 0];
    float f1 = (hv.y - mean[col + 1]) * scale[col + 1];
    float f2 = (hv.z - mean[col + 2]) * scale[col + 2];
    float f3 = (hv.w - mean[col + 3]) * scale[col + 3];
    bool anypos = (f0 > 0.f) | (f1 > 0.f) | (f2 > 0.f) | (f3 > 0.f);
    f0 = (f0 > 0.f) ? f0 : 0.f;
    f1 = (f1 > 0.f) ? f1 : 0.f;
    f2 = (f2 > 0.f) ? f2 : 0.f;
    f3 = (f3 > 0.f) ? f3 : 0.f;
    float4 ov; ov.x = f0; ov.y = f1; ov.z = f2; ov.w = f3;
    *(float4*)(hio + idx) = ov;
    if (anypos) atomicOr(&done[POSFLAG], 1u);
}

// ---------------------------------------------------------------------------
// K7: out1 = rel_repr @ w_rel   [474,128]x[128,128], f32
// ---------------------------------------------------------------------------
__global__ __launch_bounds__(128) void rel_gemm(
    const float* __restrict__ rel, const float* __restrict__ w,
    float* __restrict__ out1, u32* __restrict__ done) {
    __shared__ float rs[D];
    int t = threadIdx.x;
    int r = blockIdx.x;
    if (r == 0 && t == 0) done[MS_RELG] = 1u;
    rs[t] = rel[(size_t)r * D + t];
    __syncthreads();
    float s = 0.f;
#pragma unroll 8
    for (int k = 0; k < D; k++) s += rs[k] * w[(size_t)k * D + t];
    out1[(size_t)r * D + t] = s;
}

// ---------------------------------------------------------------------------
// K8: verifier — on failure write 2^(20+code) (f32-exact beacon) to d_out[0].
// code: 1..7 = first missing milestone (hist..relg), 8 = cursor total wrong,
// 9 = non-finite GEMM probe, 10 = zero GEMM probe, 11 = insane BN scale,
// 12 = no positive BN outputs anywhere (all-zero h output).
// ---------------------------------------------------------------------------
__global__ void verify_k(const u32* __restrict__ done, const u32* __restrict__ cursor,
                         const float* __restrict__ hprobe, const float* __restrict__ scalep,
                         float* __restrict__ out0) {
    u32 code = 0;
    for (int k = 0; k < 7; k++) {
        if (done[k] == 0u) { code = (u32)(k + 1); break; }
    }
    if (code == 0 && cursor[V - 1] != (u32)E_EDGES) code = 8;
    if (code == 0 && !isfinite(hprobe[0])) code = 9;
    if (code == 0 && !(hprobe[0] > 0.f)) code = 10;
    if (code == 0) {
        float s = scalep[0];
        if (!(s > 1e-9f && s < 1e9f)) code = 11;
    }
    if (code == 0 && done[POSFLAG] == 0u) code = 12;
    if (code != 0) out0[0] = ldexpf(1.0f, 20 + (int)code);
}

// ---------------------------------------------------------------------------
extern "C" void kernel_launch(void* const* d_in, const int* in_sizes, int n_in,
                              void* d_out, int out_size, void* d_ws, size_t ws_size,
                              hipStream_t stream) {
    const float* x        = (const float*)d_in[0];
    const float* rel_repr = (const float*)d_in[1];
    const float* enorm    = (const float*)d_in[2];
    const float* in_w     = (const float*)d_in[3];
    const float* out_w    = (const float*)d_in[4];
    const float* loop_w   = (const float*)d_in[5];
    const float* w_rel    = (const float*)d_in[6];
    const float* loop_rel = (const float*)d_in[7];
    // d_in[8] = bias: zeros; per-column constants cancel in BatchNorm anyway.
    const int* src   = (const int*)d_in[9];
    const int* dst   = (const int*)d_in[10];
    const int* etype = (const int*)d_in[11];

    float* out0 = (float*)d_out;                       // h   [V,128]  f32
    float* out1 = (float*)d_out + (size_t)V * D;       // rel [474,128] f32

    // Workspace layout — total ~2.9 MB (< proven ws_size floor of 4.35 MB)
    char* ws = (char*)d_ws;
    size_t off = 0;
    u32* cnt      = (u32*)(ws + off); off += (size_t)V * 4;
    u32* cursor   = (u32*)(ws + off); off += (size_t)V * 4;
    float* colsum = (float*)(ws + off); off += 512;
    float* colsumsq = (float*)(ws + off); off += 512;
    u32* done     = (u32*)(ws + off); off += 512;
    float* hprobe = (float*)(ws + off); off += 512;
    float* meanp  = (float*)(ws + off); off += 512;
    float* scalep = (float*)(ws + off); off += 512;
    size_t zero_bytes = off;
    u32* eid      = (u32*)(ws + off); off += (size_t)E_EDGES * 4;

    if (ws_size < off) return;

    hipMemsetAsync(d_ws, 0, zero_bytes, stream);

    hist_k<<<(E_EDGES + 255) / 256, 256, 0, stream>>>(dst, cnt, done);
    scan_k<<<1, 1024, 0, stream>>>(cnt, cursor, done);
    fill_k<<<(E_EDGES + 255) / 256, 256, 0, stream>>>(dst, cursor, eid, done);
    fused_k<<<(V + 63) / 64, 256, 0, stream>>>(x, rel_repr, loop_rel, in_w, out_w, loop_w,
                                               enorm, src, etype,
                                               cursor, cnt, eid,
                                               out0, colsum, colsumsq, done, hprobe);
    bn_finalize<<<1, 128, 0, stream>>>(colsum, colsumsq, meanp, scalep, done);
    bn_relu<<<(V * D / 4 + 255) / 256, 256, 0, stream>>>(out0, meanp, scalep, done);
    rel_gemm<<<NREL, 128, 0, stream>>>(rel_repr, w_rel, out1, done);
    verify_k<<<1, 1, 0, stream>>>(done, cursor, hprobe, scalep, out0);
}

// Round 9
// 602.890 us; speedup vs baseline: 2.0959x; 2.0959x over previous
//
#include <hip/hip_runtime.h>

// Problem constants
#define V 100000
#define E_EDGES 524288
#define HALF 262144
#define D 128
#define NREL 474
#define BN_EPS 1e-5f

#define LDK 392   // A-tile LDS row stride in u16 (384 + 8 pad, rows 16B-aligned)
#define LDB 40    // B-tile LDS row stride in u16 (32 + 8 pad)

typedef unsigned short u16;
typedef unsigned int u32;
typedef __attribute__((ext_vector_type(8))) short short8;
typedef __attribute__((ext_vector_type(4))) float f32x4;

__device__ __forceinline__ u16 f2bf(float f) {
    union { float f; u32 u; } v; v.f = f;
    u32 u = v.u;
    return (u16)((u + 0x7fffu + ((u >> 16) & 1u)) >> 16);  // RNE
}
__device__ __forceinline__ u32 pk2(float a, float b) {
    return (u32)f2bf(a) | ((u32)f2bf(b) << 16);
}

// ---------------------------------------------------------------------------
// K1: histogram of dst
// ---------------------------------------------------------------------------
__global__ __launch_bounds__(256) void hist_k(const int* __restrict__ dst, u32* __restrict__ cnt) {
    int e = blockIdx.x * 256 + threadIdx.x;
    if (e >= E_EDGES) return;
    u32 d = (u32)dst[e];
    if (d >= V) d = 0;
    atomicAdd(&cnt[d], 1u);
}

// ---------------------------------------------------------------------------
// K2: exclusive scan of cnt[V] -> cursor (single 1024-thread block)
// ---------------------------------------------------------------------------
__global__ __launch_bounds__(1024) void scan_k(const u32* __restrict__ cnt,
                                               u32* __restrict__ cursor) {
    __shared__ u32 wsum[16];
    __shared__ u32 carry_s;
    int tid = threadIdx.x, wid = tid >> 6, lane = tid & 63;
    if (tid == 0) carry_s = 0;
    __syncthreads();
    for (int base = 0; base < V; base += 1024) {
        int idx = base + tid;
        u32 v = (idx < V) ? cnt[idx] : 0u;
        u32 s = v;
#pragma unroll
        for (int o = 1; o < 64; o <<= 1) {
            u32 t = __shfl_up(s, o, 64);
            if (lane >= o) s += t;
        }
        if (lane == 63) wsum[wid] = s;
        __syncthreads();
        if (wid == 0) {
            u32 wv = (lane < 16) ? wsum[lane] : 0u;
#pragma unroll
            for (int o = 1; o < 16; o <<= 1) {
                u32 t = __shfl_up(wv, o, 64);
                if (lane >= o) wv += t;
            }
            if (lane < 16) wsum[lane] = wv;
        }
        __syncthreads();
        u32 wprev = (wid == 0) ? 0u : wsum[wid - 1];
        u32 c = carry_s;
        if (idx < V) cursor[idx] = c + s + wprev - v;   // exclusive prefix
        u32 tot = wsum[15];
        __syncthreads();
        if (tid == 0) carry_s = c + tot;
        __syncthreads();
    }
}

// ---------------------------------------------------------------------------
// K3: bucket-fill: eid[slot] = edge id, sorted by dst.
// Post: cursor[v] = bucket end; beg = cursor[v] - cnt[v].
// ---------------------------------------------------------------------------
__global__ __launch_bounds__(256) void fill_k(
    const int* __restrict__ dst, u32* __restrict__ cursor, u32* __restrict__ eid) {
    int e = blockIdx.x * 256 + threadIdx.x;
    if (e >= E_EDGES) return;
    u32 d = (u32)dst[e];
    if (d >= V) d = 0;
    u32 slot = atomicAdd(&cursor[d], 1u);
    if (slot < E_EDGES) eid[slot] = (u32)e;
}

// ---------------------------------------------------------------------------
// K4: fused gather + GEMM.  64 nodes/block, 256 threads, LDS = 60 KB.
// Phase A: per-wave gather of 16 rows (2-edge unrolled for latency overlap)
//          -> bf16 A-tile [64 x 384] = [agg_in | agg_out | x*loop_rel] in LDS.
// Phase B: A @ [in_w; out_w; loop_w] via 16x16x32 bf16 MFMA, h = /3,
//          f32 store to d_out (pre-BN), per-column sum/sumsq for BatchNorm.
// ---------------------------------------------------------------------------
__global__ __launch_bounds__(256, 1) void fused_k(
    const float* __restrict__ x, const float* __restrict__ rel, const float* __restrict__ loop_rel,
    const float* __restrict__ in_w, const float* __restrict__ out_w, const float* __restrict__ loop_w,
    const float* __restrict__ enorm,
    const int* __restrict__ src, const int* __restrict__ etype,
    const u32* __restrict__ cursor, const u32* __restrict__ cnt,
    const u32* __restrict__ eid,
    float* __restrict__ h_out, float* __restrict__ colsum, float* __restrict__ colsumsq) {
    __shared__ u16 Alds[64 * LDK];
    __shared__ u16 Bs[D * LDB];
    __shared__ float s_sum[D], s_sq[D];

    int tid = threadIdx.x, wave = tid >> 6, lane = tid & 63;
    int row0 = blockIdx.x * 64;

    if (tid < D) { s_sum[tid] = 0.f; s_sq[tid] = 0.f; }

    // ---- Phase A: gather (f32 loads, 2-edge unroll) ----
    for (int i = 0; i < 16; i++) {
        int row = wave * 16 + i;
        int gv = row0 + row;
        u32* arow = (u32*)(Alds + row * LDK);
        if (gv < V) {
            float a0 = 0.f, a1 = 0.f, b0 = 0.f, b1 = 0.f;
            float c0 = 0.f, c1 = 0.f, d0 = 0.f, d1 = 0.f;
            u32 n = cnt[gv];
            u32 end = cursor[gv];
            u32 beg = (end >= n) ? end - n : 0u;
            if (beg >= E_EDGES) { beg = 0; n = 0; }
            if (n > E_EDGES - beg) n = E_EDGES - beg;
            u32 nend = beg + n;
            u32 p = beg;
            for (; p + 2 <= nend; p += 2) {
                u32 e0 = eid[p];           if (e0 >= E_EDGES) e0 = 0;
                u32 e1 = eid[p + 1];       if (e1 >= E_EDGES) e1 = 0;
                u32 s0 = (u32)src[e0];     if (s0 >= V) s0 = 0;
                u32 s1 = (u32)src[e1];     if (s1 >= V) s1 = 0;
                u32 t0 = (u32)etype[e0];   if (t0 >= NREL) t0 = 0;
                u32 t1 = (u32)etype[e1];   if (t1 >= NREL) t1 = 0;
                float n0 = enorm[e0];
                float n1 = enorm[e1];
                float2 xv0 = *(const float2*)(x + (size_t)s0 * D + lane * 2);
                float2 xv1 = *(const float2*)(x + (size_t)s1 * D + lane * 2);
                float2 rv0 = *(const float2*)(rel + (size_t)t0 * D + lane * 2);
                float2 rv1 = *(const float2*)(rel + (size_t)t1 * D + lane * 2);
                float f00 = xv0.x * rv0.x * n0, f01 = xv0.y * rv0.y * n0;
                float f10 = xv1.x * rv1.x * n1, f11 = xv1.y * rv1.y * n1;
                if (e0 < HALF) { a0 += f00; a1 += f01; } else { b0 += f00; b1 += f01; }
                if (e1 < HALF) { c0 += f10; c1 += f11; } else { d0 += f10; d1 += f11; }
            }
            if (p < nend) {
                u32 e0 = eid[p];           if (e0 >= E_EDGES) e0 = 0;
                u32 s0 = (u32)src[e0];     if (s0 >= V) s0 = 0;
                u32 t0 = (u32)etype[e0];   if (t0 >= NREL) t0 = 0;
                float n0 = enorm[e0];
                float2 xv0 = *(const float2*)(x + (size_t)s0 * D + lane * 2);
                float2 rv0 = *(const float2*)(rel + (size_t)t0 * D + lane * 2);
                float f00 = xv0.x * rv0.x * n0, f01 = xv0.y * rv0.y * n0;
                if (e0 < HALF) { a0 += f00; a1 += f01; } else { b0 += f00; b1 += f01; }
            }
            a0 += c0; a1 += c1; b0 += d0; b1 += d1;
            float2 xv = *(const float2*)(x + (size_t)gv * D + lane * 2);
            float2 lv = *(const float2*)(loop_rel + lane * 2);
            arow[lane]       = pk2(a0, a1);                    // cols   0..127 (in)
            arow[64 + lane]  = pk2(b0, b1);                    // cols 128..255 (out)
            arow[128 + lane] = pk2(xv.x * lv.x, xv.y * lv.y);  // cols 256..383 (loop)
        } else {
            arow[lane] = 0u; arow[64 + lane] = 0u; arow[128 + lane] = 0u;
        }
    }
    __syncthreads();

    // ---- Phase B: GEMM  [64 x 384] @ [384 x 128] ----
    f32x4 acc[8];
#pragma unroll
    for (int ct = 0; ct < 8; ct++) acc[ct] = (f32x4){0.f, 0.f, 0.f, 0.f};

    int m = wave * 16 + (lane & 15);     // 0..63
    int kq = (lane >> 4) * 8;
    int bk = tid >> 3;                   // 0..31 : k within 32-step
    int bn0 = (tid & 7) * 16;            // 0..112 : n start

    for (int ks = 0; ks < 12; ks++) {
        int k0 = ks * 32;
        int seg = k0 >> 7;
        int kloc = k0 & 127;
        const float* W = (seg == 0) ? in_w : (seg == 1 ? out_w : loop_w);
#pragma unroll
        for (int j = 0; j < 16; j += 2) {
            float2 w2 = *(const float2*)(W + (size_t)(kloc + bk) * D + bn0 + j);
            Bs[(bn0 + j) * LDB + bk]     = f2bf(w2.x);
            Bs[(bn0 + j + 1) * LDB + bk] = f2bf(w2.y);
        }
        __syncthreads();
        short8 a = *(const short8*)(Alds + m * LDK + k0 + kq);
#pragma unroll
        for (int ct = 0; ct < 8; ct++) {
            short8 b = *(const short8*)(Bs + (ct * 16 + (lane & 15)) * LDB + kq);
            acc[ct] = __builtin_amdgcn_mfma_f32_16x16x32_bf16(a, b, acc[ct], 0, 0, 0);
        }
        __syncthreads();
    }

    // ---- epilogue: /3, f32 store to d_out, BN column stats ----
    int m4 = (lane >> 4) * 4;
#pragma unroll
    for (int ct = 0; ct < 8; ct++) {
        float ls = 0.f, lq = 0.f;
#pragma unroll
        for (int i = 0; i < 4; i++) {
            int gv = row0 + wave * 16 + m4 + i;
            if (gv < V) {
                float h = acc[ct][i] * (1.0f / 3.0f);
                h_out[(size_t)gv * D + ct * 16 + (lane & 15)] = h;
                ls += h; lq += h * h;
            }
        }
        atomicAdd(&s_sum[ct * 16 + (lane & 15)], ls);
        atomicAdd(&s_sq[ct * 16 + (lane & 15)], lq);
    }
    __syncthreads();
    if (tid < D) atomicAdd(&colsum[tid], s_sum[tid]);
    else atomicAdd(&colsumsq[tid - D], s_sq[tid - D]);
}

// ---------------------------------------------------------------------------
// K5: finalize BN stats
// ---------------------------------------------------------------------------
__global__ void bn_finalize(const float* __restrict__ colsum, const float* __restrict__ colsumsq,
                            float* __restrict__ mean, float* __restrict__ scale) {
    int t = threadIdx.x;
    float m = colsum[t] * (1.0f / (float)V);
    if (!isfinite(m)) m = 0.f;
    float var = colsumsq[t] * (1.0f / (float)V) - m * m;
    if (!isfinite(var) || var < 0.f) var = 0.f;
    mean[t] = m;
    scale[t] = rsqrtf(var + BN_EPS);
}

// ---------------------------------------------------------------------------
// K6: in-place BN + ReLU on d_out (f32)
// ---------------------------------------------------------------------------
__global__ __launch_bounds__(256) void bn_relu(
    float* __restrict__ hio, const float* __restrict__ mean, const float* __restrict__ scale) {
    int idx = (blockIdx.x * 256 + threadIdx.x) * 4;
    if (idx >= V * D) return;
    int col = idx & (D - 1);
    float4 hv = *(const float4*)(hio + idx);
    float f0 = (hv.x - mean[col + 0]) * scale[col + 0];
    float f1 = (hv.y - mean[col + 1]) * scale[col + 1];
    float f2 = (hv.z - mean[col + 2]) * scale[col + 2];
    float f3 = (hv.w - mean[col + 3]) * scale[col + 3];
    f0 = (f0 > 0.f) ? f0 : 0.f;
    f1 = (f1 > 0.f) ? f1 : 0.f;
    f2 = (f2 > 0.f) ? f2 : 0.f;
    f3 = (f3 > 0.f) ? f3 : 0.f;
    float4 ov; ov.x = f0; ov.y = f1; ov.z = f2; ov.w = f3;
    *(float4*)(hio + idx) = ov;
}

// ---------------------------------------------------------------------------
// K7: out1 = rel_repr @ w_rel   [474,128]x[128,128], f32
// ---------------------------------------------------------------------------
__global__ __launch_bounds__(128) void rel_gemm(
    const float* __restrict__ rel, const float* __restrict__ w, float* __restrict__ out1) {
    __shared__ float rs[D];
    int t = threadIdx.x;
    int r = blockIdx.x;
    rs[t] = rel[(size_t)r * D + t];
    __syncthreads();
    float s = 0.f;
#pragma unroll 8
    for (int k = 0; k < D; k++) s += rs[k] * w[(size_t)k * D + t];
    out1[(size_t)r * D + t] = s;
}

// ---------------------------------------------------------------------------
extern "C" void kernel_launch(void* const* d_in, const int* in_sizes, int n_in,
                              void* d_out, int out_size, void* d_ws, size_t ws_size,
                              hipStream_t stream) {
    const float* x        = (const float*)d_in[0];
    const float* rel_repr = (const float*)d_in[1];
    const float* enorm    = (const float*)d_in[2];
    const float* in_w     = (const float*)d_in[3];
    const float* out_w    = (const float*)d_in[4];
    const float* loop_w   = (const float*)d_in[5];
    const float* w_rel    = (const float*)d_in[6];
    const float* loop_rel = (const float*)d_in[7];
    // d_in[8] = bias: zeros; per-column constants cancel in BatchNorm anyway.
    const int* src   = (const int*)d_in[9];
    const int* dst   = (const int*)d_in[10];
    const int* etype = (const int*)d_in[11];

    float* out0 = (float*)d_out;                       // h   [V,128]  f32
    float* out1 = (float*)d_out + (size_t)V * D;       // rel [474,128] f32

    // Workspace layout — ~2.9 MB total
    char* ws = (char*)d_ws;
    size_t off = 0;
    u32* cnt      = (u32*)(ws + off); off += (size_t)V * 4;   // 400,000 (memset)
    float* colsum = (float*)(ws + off); off += 512;           // (memset)
    float* colsumsq = (float*)(ws + off); off += 512;         // (memset)
    size_t zero_bytes = off;                                   // 401,024
    u32* cursor   = (u32*)(ws + off); off += (size_t)V * 4;
    float* meanp  = (float*)(ws + off); off += 512;
    float* scalep = (float*)(ws + off); off += 512;
    u32* eid      = (u32*)(ws + off); off += (size_t)E_EDGES * 4;

    if (ws_size < off) return;

    hipMemsetAsync(d_ws, 0, zero_bytes, stream);

    hist_k<<<(E_EDGES + 255) / 256, 256, 0, stream>>>(dst, cnt);
    scan_k<<<1, 1024, 0, stream>>>(cnt, cursor);
    fill_k<<<(E_EDGES + 255) / 256, 256, 0, stream>>>(dst, cursor, eid);
    fused_k<<<(V + 63) / 64, 256, 0, stream>>>(x, rel_repr, loop_rel, in_w, out_w, loop_w,
                                               enorm, src, etype,
                                               cursor, cnt, eid,
                                               out0, colsum, colsumsq);
    bn_finalize<<<1, 128, 0, stream>>>(colsum, colsumsq, meanp, scalep);
    bn_relu<<<(V * D / 4 + 255) / 256, 256, 0, stream>>>(out0, meanp, scalep);
    rel_gemm<<<NREL, 128, 0, stream>>>(rel_repr, w_rel, out1);
}